// Round 6
// baseline (143.856 us; speedup 1.0000x reference)
//
#include <hip/hip_runtime.h>
#include <stdint.h>

#define BS 8
#define HH 192
#define WW 192
#define HW (HH*WW)          /* 36864 pixels per plane */
#define KK 16
#define SITES 9216          /* float4 sites per plane */
#define NQ 4                /* queries per block */
#define NW 16               /* waves per block */
#define SEGSZ 32            /* per-(query,wave) segment capacity; E ~ 2.5 */
#define UCAP 256            /* per-query merged candidate cap (4 keys/lane) */
#define PAD_FILT 4e-5f      /* filter safety: fma-vs-exact error ~1e-6 */

typedef unsigned long long u64;

// ---------- helpers ----------

__device__ __forceinline__ uint32_t fkey(float f) {
    uint32_t u = __float_as_uint(f);
    uint32_t mask = (uint32_t)((int32_t)u >> 31) | 0x80000000u;
    return u ^ mask;
}
__device__ __forceinline__ float inv_fkey(uint32_t v) {
    uint32_t u = (v & 0x80000000u) ? (v ^ 0x80000000u) : ~v;
    return __uint_as_float(u);
}

__device__ __forceinline__ u64 umin64(u64 a, u64 b) { return a < b ? a : b; }

__device__ __forceinline__ uint32_t mbcnt64(u64 m) {
    return __builtin_amdgcn_mbcnt_hi((uint32_t)(m >> 32),
            __builtin_amdgcn_mbcnt_lo((uint32_t)m, 0));
}

__device__ __forceinline__ u64 wave_min_u64(u64 v) {   // fallback path only
    #pragma unroll
    for (int off = 32; off >= 1; off >>= 1) {
        uint32_t lo = (uint32_t)v, hi = (uint32_t)(v >> 32);
        lo = __shfl_xor(lo, off, 64);
        hi = __shfl_xor(hi, off, 64);
        u64 o = ((u64)hi << 32) | lo;
        v = umin64(v, o);
    }
    return v;
}

// sorted ascending insertion, 16 deep (fallback path only)
__device__ __forceinline__ void insert64(u64 (&kept)[KK], u64 key) {
    #pragma unroll
    for (int j = KK - 1; j >= 1; --j) {
        u64 a = kept[j - 1];
        u64 mn = umin64(kept[j], key);
        kept[j] = (key < a) ? a : mn;
    }
    kept[0] = umin64(kept[0], key);
}

// exact (reference-rounded) similarity pieces — bit-identical to validated kernel
__device__ __forceinline__ float exact_rsq(float a, float b, float c) {
    return __fadd_rn(__fadd_rn(__fmul_rn(a, a), __fmul_rn(b, b)), __fmul_rn(c, c));
}
__device__ __forceinline__ float exact_sim(float c0, float c1, float c2, float rsq, float4 pq) {
    float cr = __fadd_rn(__fadd_rn(__fmul_rn(c0, pq.x), __fmul_rn(c1, pq.y)), __fmul_rn(c2, pq.z));
    return __fadd_rn(__fsub_rn(rsq, __fmul_rn(2.0f, cr)), pq.w);
}

// loss-term tracking (fallback path): strict < keeps first (lowest-rank) min
#define LOSS_STEP(gmv)                                                   \
{                                                                        \
    uint32_t idxv = (uint32_t)(gmv);                                     \
    float tx = (float)(idxv % WW) / 192.0f;                              \
    float ty = (float)(idxv / WW) / 192.0f;                              \
    float ddx = __fsub_rn(px1, tx);                                      \
    float ddy = __fsub_rn(py1, ty);                                      \
    float dd = __fadd_rn(__fmul_rn(ddx, ddx), __fmul_rn(ddy, ddy));      \
    if (dd < dmin) { dmin = dd; btx = tx; bty = ty; }                    \
}

// ---------- fused kernel: block = (image, 4 queries), 1024 threads ----------
// P0: pooled/psq per query (exact, verbatim reference rounding)
// P1: sample sites 0..4095 once, shared across 4 queries; per-thread per-query
//     MAX d (sound threshold source); keys -> LDS (u32 alias of seg64)
// P2: waves 0..3 — 20-step ballot-count binsearch; hi stays a sound upper
//     bound on the sample 16th-smallest key at every step; h = -d(hi) - PAD
// P3: all 16 waves scan the full image once (1-deep prefetch); shared
//     -0.5*rsq; on pass, compute EXACT (simkey,pidx) in-register and push the
//     u64 to a private per-(query,wave) LDS segment (ballot+mbcnt, no atomics)
// P4: waves 0..3 — compact u64 keys (no global gather), exact top-16 via
//     stage-A ballot binsearch (+rare stage-B only on float-ties),
//     lexicographic (dd,key) argmin == reference rank-order tie-break
__global__ __launch_bounds__(1024, 8) void fused_kernel(const float* __restrict__ pred,
                                                        const float* __restrict__ ref,
                                                        float* __restrict__ partial) {
    __shared__ u64 seg64[NQ * NW * SEGSZ];    // 16 KB (u32-aliased for P1/P2)
    __shared__ u64 comp64[NQ * UCAP];         // 8 KB
    __shared__ uint32_t scnts[NQ * NW];
    __shared__ float4 spool[NQ];
    __shared__ float shq[NQ];
    uint32_t* mx = (uint32_t*)seg64;          // 4096 u32 keys

    int tid  = threadIdx.x;
    int lane = tid & 63;
    int wid  = tid >> 6;              // 0..15
    int b  = blockIdx.x & 7;          // XCD swizzle: image b -> XCD b
    int qg = blockIdx.x >> 3;         // 0..63

    // ---- P0 ----
    if (tid < NQ) {
        int l = qg * NQ + tid;
        int i = l * BS + b;           // scrambled flat grid row
        int b2 = i >> 8, l2 = i & 255;
        const float* pr = pred + ((b2 * 256 + l2) * 8);
        float x = pr[0], y = pr[1];
        float fx = rintf(__fsub_rn(__fmul_rn(x, 192.0f), 0.5f));
        float fy = rintf(__fsub_rn(__fmul_rn(y, 192.0f), 0.5f));
        int ix = (int)fx, iy = (int)fy;
        int inb = (ix >= 0 && ix < WW && iy >= 0 && iy < HH) ? 1 : 0;
        int ixc = min(max(ix, 0), WW - 1);
        int iyc = min(max(iy, 0), HH - 1);
        float m = (float)inb;
        const float* img = ref + b * 3 * HW + iyc * WW + ixc;
        float p0 = __fmul_rn(img[0], m);
        float p1 = __fmul_rn(img[HW], m);
        float p2 = __fmul_rn(img[2 * HW], m);
        float psq = __fadd_rn(__fadd_rn(__fmul_rn(p0, p0), __fmul_rn(p1, p1)),
                              __fmul_rn(p2, p2));
        spool[tid] = make_float4(p0, p1, p2, psq);
    }
    __syncthreads();

    const float4* p0g = (const float4*)(ref + (size_t)b * 3 * HW);
    float qx[NQ], qy[NQ], qz[NQ];
    #pragma unroll
    for (int q = 0; q < NQ; ++q) {
        float4 s = spool[q];
        qx[q] = s.x; qy[q] = s.y; qz[q] = s.z;
    }

    // ---- P1: shared sampling, per-thread per-query max ----
    float md0 = -3.4e38f, md1 = -3.4e38f, md2 = -3.4e38f, md3 = -3.4e38f;
    #pragma unroll 1
    for (int it = 0; it < 4; ++it) {
        int site = tid + it * 1024;
        float4 a0 = p0g[site], a1 = p0g[site + SITES], a2 = p0g[site + 2 * SITES];
        #define SAMP(comp)                                                              \
        {                                                                               \
            float nr = -0.5f * fmaf(a2.comp, a2.comp, fmaf(a1.comp, a1.comp,            \
                              a0.comp * a0.comp));                                      \
            float d0_ = fmaf(a2.comp, qz[0], fmaf(a1.comp, qy[0], fmaf(a0.comp, qx[0], nr))); \
            float d1_ = fmaf(a2.comp, qz[1], fmaf(a1.comp, qy[1], fmaf(a0.comp, qx[1], nr))); \
            float d2_ = fmaf(a2.comp, qz[2], fmaf(a1.comp, qy[2], fmaf(a0.comp, qx[2], nr))); \
            float d3_ = fmaf(a2.comp, qz[3], fmaf(a1.comp, qy[3], fmaf(a0.comp, qx[3], nr))); \
            md0 = fmaxf(md0, d0_); md1 = fmaxf(md1, d1_);                               \
            md2 = fmaxf(md2, d2_); md3 = fmaxf(md3, d3_);                               \
        }
        SAMP(x) SAMP(y) SAMP(z) SAMP(w)
        #undef SAMP
    }
    mx[0 * 1024 + tid] = fkey(-md0);
    mx[1 * 1024 + tid] = fkey(-md1);
    mx[2 * 1024 + tid] = fkey(-md2);
    mx[3 * 1024 + tid] = fkey(-md3);

    // waves that skip P2: issue P3's first-site loads now (fly across barrier)
    float4 n0, n1, n2;
    if (wid >= NQ) {
        n0 = p0g[tid]; n1 = p0g[tid + SITES]; n2 = p0g[tid + 2 * SITES];
    }
    __syncthreads();

    // ---- P2: per-query threshold (wave w -> query w), 20-step binsearch ----
    if (wid < NQ) {
        uint32_t v[16];
        #pragma unroll
        for (int j = 0; j < 16; ++j) v[j] = mx[wid * 1024 + lane + 64 * j];
        uint32_t lo = 0u, hi = 0xFFFFFFFFu;
        #pragma unroll 1
        for (int t = 0; t < 20; ++t) {
            uint32_t mid = lo + ((hi - lo) >> 1);
            int c = 0;
            #pragma unroll
            for (int j = 0; j < 16; ++j) c += (int)__popcll(__ballot(v[j] <= mid));
            if (c >= KK) hi = mid; else lo = mid + 1;
        }
        float hval = -inv_fkey(hi) - PAD_FILT;
        if (qg == 63 && wid == 3) hval = 3.0e38f;   // l==255: never pass
        if (lane == 0) shq[wid] = hval;
        // now issue our P3 first-site loads (in flight across the barrier)
        n0 = p0g[tid]; n1 = p0g[tid + SITES]; n2 = p0g[tid + 2 * SITES];
    }
    __syncthreads();

    // ---- P3: full-image scan, exact-key push into private segments ----
    float hq0 = shq[0], hq1 = shq[1], hq2 = shq[2], hq3 = shq[3];
    uint32_t scq0 = 0, scq1 = 0, scq2 = 0, scq3 = 0;
    int site3 = tid;

    #pragma unroll 1
    for (int it = 0; it < 9; ++it) {           // 9*1024 = 9216 sites
        float4 a0 = n0, a1 = n1, a2 = n2;
        int sn = (it < 8) ? (site3 + 1024) : site3;   // clamped last prefetch
        n0 = p0g[sn]; n1 = p0g[sn + SITES]; n2 = p0g[sn + 2 * SITES];
        int base = site3 * 4;

        float nrx = -0.5f * fmaf(a2.x, a2.x, fmaf(a1.x, a1.x, a0.x * a0.x));
        float nry = -0.5f * fmaf(a2.y, a2.y, fmaf(a1.y, a1.y, a0.y * a0.y));
        float nrz = -0.5f * fmaf(a2.z, a2.z, fmaf(a1.z, a1.z, a0.z * a0.z));
        float nrw = -0.5f * fmaf(a2.w, a2.w, fmaf(a1.w, a1.w, a0.w * a0.w));

        #define PUSHC(cv0, cv1, cv2, dj, mj, eidx)                                      \
            if (dj >= hqv_) {                                                           \
                uint32_t s_ = c + mbcnt64(mj);                                          \
                if (s_ < SEGSZ) {                                                       \
                    float rs_ = exact_rsq(cv0, cv1, cv2);                               \
                    float sx_ = exact_sim(cv0, cv1, cv2, rs_, pqv_);                    \
                    seg64[sb + s_] = ((u64)fkey(sx_) << 32) | (uint32_t)(base + eidx);  \
                }                                                                       \
            }                                                                           \
            c += (uint32_t)__popcll(mj);

        #define QPUSH(qi, hqv, scq)                                                     \
        {                                                                               \
            float hqv_ = hqv;                                                           \
            float d0 = fmaf(a2.x, qz[qi], fmaf(a1.x, qy[qi], fmaf(a0.x, qx[qi], nrx))); \
            float d1 = fmaf(a2.y, qz[qi], fmaf(a1.y, qy[qi], fmaf(a0.y, qx[qi], nry))); \
            float d2 = fmaf(a2.z, qz[qi], fmaf(a1.z, qy[qi], fmaf(a0.z, qx[qi], nrz))); \
            float d3 = fmaf(a2.w, qz[qi], fmaf(a1.w, qy[qi], fmaf(a0.w, qx[qi], nrw))); \
            u64 m0 = __ballot(d0 >= hqv_);                                              \
            u64 m1 = __ballot(d1 >= hqv_);                                              \
            u64 m2 = __ballot(d2 >= hqv_);                                              \
            u64 m3 = __ballot(d3 >= hqv_);                                              \
            if (m0 | m1 | m2 | m3) {          /* wave-uniform scalar branch */          \
                float4 pqv_ = spool[qi];                                                \
                uint32_t sb = ((qi) * NW + wid) * SEGSZ;                                \
                uint32_t c = scq;                                                       \
                PUSHC(a0.x, a1.x, a2.x, d0, m0, 0)                                      \
                PUSHC(a0.y, a1.y, a2.y, d1, m1, 1)                                      \
                PUSHC(a0.z, a1.z, a2.z, d2, m2, 2)                                      \
                PUSHC(a0.w, a1.w, a2.w, d3, m3, 3)                                      \
                scq = c;                                                                \
            }                                                                           \
        }
        QPUSH(0, hq0, scq0) QPUSH(1, hq1, scq1) QPUSH(2, hq2, scq2) QPUSH(3, hq3, scq3)
        #undef QPUSH
        #undef PUSHC
        site3 = sn;
    }
    if (lane == 0) {
        scnts[0 * NW + wid] = scq0; scnts[1 * NW + wid] = scq1;
        scnts[2 * NW + wid] = scq2; scnts[3 * NW + wid] = scq3;
    }
    __syncthreads();

    // ---- P4: compact + exact top-16 + loss (wave w -> query w) ----
    if (wid < NQ) {
        int l  = qg * NQ + wid;
        int bl = b * 256 + l;
        if (l == 255) {                    // its top-16 feeds only excluded row 0
            if (lane == 0) partial[bl] = 0.0f;
        } else {
            bool ovf = false;
            uint32_t pref = 0;
            #pragma unroll
            for (int j = 0; j < NW; ++j) {
                uint32_t c = scnts[wid * NW + j];
                ovf = ovf || (c > SEGSZ);
                uint32_t cc = min(c, (uint32_t)SEGSZ);
                if (lane < cc && pref + lane < UCAP)
                    comp64[wid * UCAP + pref + lane] =
                        seg64[(wid * NW + j) * SEGSZ + lane];
                pref += cc;
            }
            uint32_t U = pref;
            if (U > UCAP) ovf = true;

            float px1 = pred[(size_t)(bl + 1) * 8 + 0];
            float py1 = pred[(size_t)(bl + 1) * 8 + 1];
            float4 pqv = spool[wid];
            const float* rb = ref + (size_t)b * 3 * HW;

            if (!ovf) {
                // candidate keys straight from LDS (no global gather)
                uint32_t kh0, kh1, kh2, kh3, kl0, kl1, kl2, kl3;
                #define LOADJ(jj, kh, kl)                                      \
                {                                                              \
                    uint32_t e = (jj) * 64 + lane;                             \
                    uint32_t h_ = 0xFFFFFFFFu, l_ = 0xFFFFFFFFu;               \
                    if (e < U) {                                               \
                        u64 v_ = comp64[wid * UCAP + e];                       \
                        h_ = (uint32_t)(v_ >> 32); l_ = (uint32_t)v_;          \
                    }                                                          \
                    kh = h_; kl = l_;                                          \
                }
                LOADJ(0, kh0, kl0) LOADJ(1, kh1, kl1) LOADJ(2, kh2, kl2) LOADJ(3, kh3, kl3)
                #undef LOADJ

                // stage A: smallest H with #{khi <= H} >= 16 (exact; padding
                // 0xFFFFFFFF can't distort since U >= 16 real finite keys)
                uint32_t lo = 0u, hi = 0xFFFFFFFFu;
                #pragma unroll 1
                for (int t = 0; t < 32; ++t) {
                    uint32_t mid = lo + ((hi - lo) >> 1);
                    int c = (int)__popcll(__ballot(kh0 <= mid))
                          + (int)__popcll(__ballot(kh1 <= mid))
                          + (int)__popcll(__ballot(kh2 <= mid))
                          + (int)__popcll(__ballot(kh3 <= mid));
                    if (c >= KK) hi = mid; else lo = mid + 1;
                }
                uint32_t Hh = hi;
                int c1 = (int)__popcll(__ballot(kh0 < Hh))
                       + (int)__popcll(__ballot(kh1 < Hh))
                       + (int)__popcll(__ballot(kh2 < Hh))
                       + (int)__popcll(__ballot(kh3 < Hh));
                u64 e0 = __ballot(kh0 == Hh), e1 = __ballot(kh1 == Hh);
                u64 e2 = __ballot(kh2 == Hh), e3 = __ballot(kh3 == Hh);
                int ec = (int)__popcll(e0) + (int)__popcll(e1)
                       + (int)__popcll(e2) + (int)__popcll(e3);
                int need = KK - c1;                    // 1..16; ec >= need by minimality
                uint32_t Lh = 0xFFFFFFFFu;
                if (ec != need) {
                    // float-tie among sims at the cut (rare): resolve by pidx
                    lo = 0u; hi = 0xFFFFFFFFu;
                    #pragma unroll 1
                    for (int t = 0; t < 32; ++t) {
                        uint32_t mid = lo + ((hi - lo) >> 1);
                        int c = (int)__popcll(e0 & __ballot(kl0 <= mid))
                              + (int)__popcll(e1 & __ballot(kl1 <= mid))
                              + (int)__popcll(e2 & __ballot(kl2 <= mid))
                              + (int)__popcll(e3 & __ballot(kl3 <= mid));
                        if (c >= need) hi = mid; else lo = mid + 1;
                    }
                    Lh = hi;
                }

                // lexicographic min of (ddbits, khi, klo) over the selected 16
                // == argmin over rank-ordered targets, first-min tie-break
                uint32_t bd = 0xFFFFFFFFu, bh = 0xFFFFFFFFu, bo = 0xFFFFFFFFu;
                #define SELJ(kh, kl)                                                    \
                {                                                                       \
                    bool sel = (kh < Hh) || (kh == Hh && kl <= Lh);                     \
                    if (sel) {                                                          \
                        uint32_t idxv = kl;                                             \
                        float tx = (float)(idxv % WW) / 192.0f;                         \
                        float ty = (float)(idxv / WW) / 192.0f;                         \
                        float ddx = __fsub_rn(px1, tx);                                 \
                        float ddy = __fsub_rn(py1, ty);                                 \
                        float dd = __fadd_rn(__fmul_rn(ddx, ddx), __fmul_rn(ddy, ddy)); \
                        uint32_t db = __float_as_uint(dd);   /* dd>=0: monotone */      \
                        bool lt = (db < bd) ||                                          \
                                  (db == bd && (kh < bh || (kh == bh && kl < bo)));     \
                        if (lt) { bd = db; bh = kh; bo = kl; }                          \
                    }                                                                   \
                }
                SELJ(kh0, kl0) SELJ(kh1, kl1) SELJ(kh2, kl2) SELJ(kh3, kl3)
                #undef SELJ
                #pragma unroll
                for (int off = 32; off >= 1; off >>= 1) {
                    uint32_t od = __shfl_xor(bd, off, 64);
                    uint32_t oh = __shfl_xor(bh, off, 64);
                    uint32_t oo = __shfl_xor(bo, off, 64);
                    bool lt = (od < bd) ||
                              (od == bd && (oh < bh || (oh == bh && oo < bo)));
                    if (lt) { bd = od; bh = oh; bo = oo; }
                }
                if (lane == 0) {
                    uint32_t idxv = bo;
                    float tx = (float)(idxv % WW) / 192.0f;
                    float ty = (float)(idxv / WW) / 192.0f;
                    float ex = __fsub_rn(px1, tx);
                    float ey = __fsub_rn(py1, ty);
                    partial[bl] = __fadd_rn(__fmul_rn(ex, ex), __fmul_rn(ey, ey));
                }
            } else {
                // safety net (P ~ 1e-20): exact full rescan for this query
                float dmin = 3.4e38f, btx = 0.0f, bty = 0.0f;
                u64 kept16[KK];
                #pragma unroll
                for (int j = 0; j < KK; ++j) kept16[j] = ~0ull;
                const float4* pg = (const float4*)rb;
                #pragma unroll 1
                for (int st = lane; st < SITES; st += 64) {
                    float4 a0 = pg[st], a1 = pg[st + SITES], a2 = pg[st + 2 * SITES];
                    int base = st * 4;
                    #define FB(comp, ei)                                                \
                    {                                                                   \
                        float rs = exact_rsq(a0.comp, a1.comp, a2.comp);                \
                        float sx = exact_sim(a0.comp, a1.comp, a2.comp, rs, pqv);       \
                        u64 key = ((u64)fkey(sx) << 32) | (uint32_t)(base + (ei));      \
                        if (key < kept16[KK - 1]) insert64(kept16, key);                \
                    }
                    FB(x, 0) FB(y, 1) FB(z, 2) FB(w, 3)
                    #undef FB
                }
                #pragma unroll 1
                for (int rnd = 0; rnd < 16; ++rnd) {
                    u64 gm = wave_min_u64(kept16[0]);
                    if (kept16[0] == gm) {        // exactly one lane (unique keys)
                        #pragma unroll
                        for (int j = 0; j < KK - 1; ++j) kept16[j] = kept16[j + 1];
                        kept16[KK - 1] = ~0ull;
                    }
                    LOSS_STEP(gm)
                }
                if (lane == 0) {
                    float ex = __fsub_rn(px1, btx);
                    float ey = __fsub_rn(py1, bty);
                    partial[bl] = __fadd_rn(__fmul_rn(ex, ex), __fmul_rn(ey, ey));
                }
            }
        }
    }
}

// ---------- reduce 2048 partials -> mean ----------
__global__ __launch_bounds__(256) void reduce_kernel(const float* __restrict__ partial,
                                                     float* __restrict__ out) {
    __shared__ double sred[256];
    double a = 0.0;
    #pragma unroll
    for (int i = 0; i < 8; ++i) a += (double)partial[i * 256 + threadIdx.x];
    sred[threadIdx.x] = a;
    __syncthreads();
    for (int s = 128; s > 0; s >>= 1) {
        if (threadIdx.x < s) sred[threadIdx.x] += sred[threadIdx.x + s];
        __syncthreads();
    }
    if (threadIdx.x == 0) out[0] = (float)(sred[0] / 2040.0);
}

// ---------- launch ----------
extern "C" void kernel_launch(void* const* d_in, const int* in_sizes, int n_in,
                              void* d_out, int out_size, void* d_ws, size_t ws_size,
                              hipStream_t stream) {
    const float* pred = (const float*)d_in[0];   // (8,256,8) f32
    const float* ref  = (const float*)d_in[1];   // (8,3,192,192) f32
    float* out = (float*)d_out;

    float* partial = (float*)d_ws;               // 2048 floats, fully overwritten

    fused_kernel <<<512, 1024, 0, stream>>>(pred, ref, partial);
    reduce_kernel<<<  1,  256, 0, stream>>>(partial, out);
}

// Round 7
// 143.735 us; speedup vs baseline: 1.0008x; 1.0008x over previous
//
#include <hip/hip_runtime.h>
#include <stdint.h>

#define BS 8
#define HH 192
#define WW 192
#define HW (HH*WW)          /* 36864 pixels per plane */
#define KK 16
#define SITES 9216          /* float4 sites per plane */
#define NQ 4                /* queries per block */
#define NW 16               /* waves per block */
#define SEGSZ 32            /* per-(query,wave) segment capacity; E ~ 2.5 */
#define UCAP 256            /* per-query merged candidate cap (4 keys/lane) */
#define PAD_FILT 4e-5f      /* filter safety: fma-vs-exact error ~1e-6 */

typedef unsigned long long u64;

// ---------- helpers ----------

__device__ __forceinline__ uint32_t fkey(float f) {
    uint32_t u = __float_as_uint(f);
    uint32_t mask = (uint32_t)((int32_t)u >> 31) | 0x80000000u;
    return u ^ mask;
}
__device__ __forceinline__ float inv_fkey(uint32_t v) {
    uint32_t u = (v & 0x80000000u) ? (v ^ 0x80000000u) : ~v;
    return __uint_as_float(u);
}

__device__ __forceinline__ u64 umin64(u64 a, u64 b) { return a < b ? a : b; }

__device__ __forceinline__ uint32_t mbcnt64(u64 m) {
    return __builtin_amdgcn_mbcnt_hi((uint32_t)(m >> 32),
            __builtin_amdgcn_mbcnt_lo((uint32_t)m, 0));
}

__device__ __forceinline__ u64 wave_min_u64(u64 v) {   // fallback path only
    #pragma unroll
    for (int off = 32; off >= 1; off >>= 1) {
        uint32_t lo = (uint32_t)v, hi = (uint32_t)(v >> 32);
        lo = __shfl_xor(lo, off, 64);
        hi = __shfl_xor(hi, off, 64);
        u64 o = ((u64)hi << 32) | lo;
        v = umin64(v, o);
    }
    return v;
}

// sorted ascending insertion, 16 deep (fallback path only)
__device__ __forceinline__ void insert64(u64 (&kept)[KK], u64 key) {
    #pragma unroll
    for (int j = KK - 1; j >= 1; --j) {
        u64 a = kept[j - 1];
        u64 mn = umin64(kept[j], key);
        kept[j] = (key < a) ? a : mn;
    }
    kept[0] = umin64(kept[0], key);
}

// exact (reference-rounded) similarity pieces — bit-identical to validated kernel
__device__ __forceinline__ float exact_rsq(float a, float b, float c) {
    return __fadd_rn(__fadd_rn(__fmul_rn(a, a), __fmul_rn(b, b)), __fmul_rn(c, c));
}
__device__ __forceinline__ float exact_sim(float c0, float c1, float c2, float rsq,
                                           float qx_, float qy_, float qz_, float qw_) {
    float cr = __fadd_rn(__fadd_rn(__fmul_rn(c0, qx_), __fmul_rn(c1, qy_)), __fmul_rn(c2, qz_));
    return __fadd_rn(__fsub_rn(rsq, __fmul_rn(2.0f, cr)), qw_);
}

// loss-term tracking (fallback path): strict < keeps first (lowest-rank) min
#define LOSS_STEP(gmv)                                                   \
{                                                                        \
    uint32_t idxv = (uint32_t)(gmv);                                     \
    float tx = (float)(idxv % WW) / 192.0f;                              \
    float ty = (float)(idxv / WW) / 192.0f;                              \
    float ddx = __fsub_rn(px1, tx);                                      \
    float ddy = __fsub_rn(py1, ty);                                      \
    float dd = __fadd_rn(__fmul_rn(ddx, ddx), __fmul_rn(ddy, ddy));      \
    if (dd < dmin) { dmin = dd; btx = tx; bty = ty; }                    \
}

// ---------- fused kernel: block = (image, 4 queries), 1024 threads ----------
// P0: pooled/psq per query (exact, verbatim reference rounding)
// P1: sample sites 0..4095 once, shared across 4 queries; per-thread per-query
//     MAX d (sound threshold source); keys -> LDS (u32 alias of seg64)
// P2: waves 0..3 — 20-step ballot-count binsearch; hi stays a sound upper
//     bound on the sample 16th-smallest key at every step; h = -d(hi) - PAD
// P3: all 16 waves scan the full image once; shared -0.5*rsq; on pass,
//     compute EXACT (simkey,pidx) in-register (psq via 1 LDS scalar read in
//     the rare uniform branch) and push u64 to a private per-(query,wave)
//     LDS segment (ballot+mbcnt, no atomics). NO prefetch, NO live float4
//     pooled vector: keeps live set <= 64 VGPR so launch_bounds(1024,8)
//     (2 blocks/CU) holds WITHOUT scratch spill (round-6 lesson: spill
//     traffic was 83 MB/dispatch and doubled kernel time).
// P4: waves 0..3 — compact u64 keys from LDS (no global gather), exact
//     top-16 via stage-A ballot binsearch (+rare stage-B on float-ties),
//     lexicographic (dd,key) argmin == reference rank-order tie-break
__global__ __launch_bounds__(1024, 8) void fused_kernel(const float* __restrict__ pred,
                                                        const float* __restrict__ ref,
                                                        float* __restrict__ partial) {
    __shared__ u64 seg64[NQ * NW * SEGSZ];    // 16 KB (u32-aliased for P1/P2)
    __shared__ u64 comp64[NQ * UCAP];         // 8 KB
    __shared__ uint32_t scnts[NQ * NW];
    __shared__ float4 spool[NQ];
    __shared__ float shq[NQ];
    uint32_t* mx = (uint32_t*)seg64;          // 4096 u32 keys

    int tid  = threadIdx.x;
    int lane = tid & 63;
    int wid  = tid >> 6;              // 0..15
    int b  = blockIdx.x & 7;          // XCD swizzle: image b -> XCD b
    int qg = blockIdx.x >> 3;         // 0..63

    // ---- P0 ----
    if (tid < NQ) {
        int l = qg * NQ + tid;
        int i = l * BS + b;           // scrambled flat grid row
        int b2 = i >> 8, l2 = i & 255;
        const float* pr = pred + ((b2 * 256 + l2) * 8);
        float x = pr[0], y = pr[1];
        float fx = rintf(__fsub_rn(__fmul_rn(x, 192.0f), 0.5f));
        float fy = rintf(__fsub_rn(__fmul_rn(y, 192.0f), 0.5f));
        int ix = (int)fx, iy = (int)fy;
        int inb = (ix >= 0 && ix < WW && iy >= 0 && iy < HH) ? 1 : 0;
        int ixc = min(max(ix, 0), WW - 1);
        int iyc = min(max(iy, 0), HH - 1);
        float m = (float)inb;
        const float* img = ref + b * 3 * HW + iyc * WW + ixc;
        float p0 = __fmul_rn(img[0], m);
        float p1 = __fmul_rn(img[HW], m);
        float p2 = __fmul_rn(img[2 * HW], m);
        float psq = __fadd_rn(__fadd_rn(__fmul_rn(p0, p0), __fmul_rn(p1, p1)),
                              __fmul_rn(p2, p2));
        spool[tid] = make_float4(p0, p1, p2, psq);
    }
    __syncthreads();

    const float4* p0g = (const float4*)(ref + (size_t)b * 3 * HW);
    float qx[NQ], qy[NQ], qz[NQ];
    #pragma unroll
    for (int q = 0; q < NQ; ++q) {
        float4 s = spool[q];
        qx[q] = s.x; qy[q] = s.y; qz[q] = s.z;
    }

    // ---- P1: shared sampling, per-thread per-query max ----
    float md0 = -3.4e38f, md1 = -3.4e38f, md2 = -3.4e38f, md3 = -3.4e38f;
    #pragma unroll 1
    for (int it = 0; it < 4; ++it) {
        int site = tid + it * 1024;
        float4 a0 = p0g[site], a1 = p0g[site + SITES], a2 = p0g[site + 2 * SITES];
        #define SAMP(comp)                                                              \
        {                                                                               \
            float nr = -0.5f * fmaf(a2.comp, a2.comp, fmaf(a1.comp, a1.comp,            \
                              a0.comp * a0.comp));                                      \
            float d0_ = fmaf(a2.comp, qz[0], fmaf(a1.comp, qy[0], fmaf(a0.comp, qx[0], nr))); \
            float d1_ = fmaf(a2.comp, qz[1], fmaf(a1.comp, qy[1], fmaf(a0.comp, qx[1], nr))); \
            float d2_ = fmaf(a2.comp, qz[2], fmaf(a1.comp, qy[2], fmaf(a0.comp, qx[2], nr))); \
            float d3_ = fmaf(a2.comp, qz[3], fmaf(a1.comp, qy[3], fmaf(a0.comp, qx[3], nr))); \
            md0 = fmaxf(md0, d0_); md1 = fmaxf(md1, d1_);                               \
            md2 = fmaxf(md2, d2_); md3 = fmaxf(md3, d3_);                               \
        }
        SAMP(x) SAMP(y) SAMP(z) SAMP(w)
        #undef SAMP
    }
    mx[0 * 1024 + tid] = fkey(-md0);
    mx[1 * 1024 + tid] = fkey(-md1);
    mx[2 * 1024 + tid] = fkey(-md2);
    mx[3 * 1024 + tid] = fkey(-md3);
    __syncthreads();

    // ---- P2: per-query threshold (wave w -> query w), 20-step binsearch ----
    if (wid < NQ) {
        uint32_t v[16];
        #pragma unroll
        for (int j = 0; j < 16; ++j) v[j] = mx[wid * 1024 + lane + 64 * j];
        uint32_t lo = 0u, hi = 0xFFFFFFFFu;
        #pragma unroll 1
        for (int t = 0; t < 20; ++t) {
            uint32_t mid = lo + ((hi - lo) >> 1);
            int c = 0;
            #pragma unroll
            for (int j = 0; j < 16; ++j) c += (int)__popcll(__ballot(v[j] <= mid));
            if (c >= KK) hi = mid; else lo = mid + 1;
        }
        float hval = -inv_fkey(hi) - PAD_FILT;
        if (qg == 63 && wid == 3) hval = 3.0e38f;   // l==255: never pass
        if (lane == 0) shq[wid] = hval;
    }
    __syncthreads();

    // ---- P3: full-image scan, exact-key push into private segments ----
    float hq0 = shq[0], hq1 = shq[1], hq2 = shq[2], hq3 = shq[3];
    uint32_t scq0 = 0, scq1 = 0, scq2 = 0, scq3 = 0;

    #pragma unroll 1
    for (int it = 0; it < 9; ++it) {           // 9*1024 = 9216 sites
        int site3 = tid + it * 1024;
        float4 a0 = p0g[site3], a1 = p0g[site3 + SITES], a2 = p0g[site3 + 2 * SITES];
        int base = site3 * 4;

        float nrx = -0.5f * fmaf(a2.x, a2.x, fmaf(a1.x, a1.x, a0.x * a0.x));
        float nry = -0.5f * fmaf(a2.y, a2.y, fmaf(a1.y, a1.y, a0.y * a0.y));
        float nrz = -0.5f * fmaf(a2.z, a2.z, fmaf(a1.z, a1.z, a0.z * a0.z));
        float nrw = -0.5f * fmaf(a2.w, a2.w, fmaf(a1.w, a1.w, a0.w * a0.w));

        #define PUSHC(cv0, cv1, cv2, dj, mj, eidx)                                      \
            if (dj >= hqv_) {                                                           \
                uint32_t s_ = c + mbcnt64(mj);                                          \
                if (s_ < SEGSZ) {                                                       \
                    float rs_ = exact_rsq(cv0, cv1, cv2);                               \
                    float sx_ = exact_sim(cv0, cv1, cv2, rs_,                           \
                                          qx[qi_], qy[qi_], qz[qi_], pw_);              \
                    seg64[sb + s_] = ((u64)fkey(sx_) << 32) | (uint32_t)(base + eidx);  \
                }                                                                       \
            }                                                                           \
            c += (uint32_t)__popcll(mj);

        #define QPUSH(qi, hqv, scq)                                                     \
        {                                                                               \
            const int qi_ = qi;                                                         \
            float hqv_ = hqv;                                                           \
            float d0 = fmaf(a2.x, qz[qi], fmaf(a1.x, qy[qi], fmaf(a0.x, qx[qi], nrx))); \
            float d1 = fmaf(a2.y, qz[qi], fmaf(a1.y, qy[qi], fmaf(a0.y, qx[qi], nry))); \
            float d2 = fmaf(a2.z, qz[qi], fmaf(a1.z, qy[qi], fmaf(a0.z, qx[qi], nrz))); \
            float d3 = fmaf(a2.w, qz[qi], fmaf(a1.w, qy[qi], fmaf(a0.w, qx[qi], nrw))); \
            u64 m0 = __ballot(d0 >= hqv_);                                              \
            u64 m1 = __ballot(d1 >= hqv_);                                              \
            u64 m2 = __ballot(d2 >= hqv_);                                              \
            u64 m3 = __ballot(d3 >= hqv_);                                              \
            if (m0 | m1 | m2 | m3) {          /* wave-uniform scalar branch */          \
                float pw_ = spool[qi].w;       /* 1 LDS scalar, rare path */            \
                uint32_t sb = ((qi) * NW + wid) * SEGSZ;                                \
                uint32_t c = scq;                                                       \
                PUSHC(a0.x, a1.x, a2.x, d0, m0, 0)                                      \
                PUSHC(a0.y, a1.y, a2.y, d1, m1, 1)                                      \
                PUSHC(a0.z, a1.z, a2.z, d2, m2, 2)                                      \
                PUSHC(a0.w, a1.w, a2.w, d3, m3, 3)                                      \
                scq = c;                                                                \
            }                                                                           \
        }
        QPUSH(0, hq0, scq0) QPUSH(1, hq1, scq1) QPUSH(2, hq2, scq2) QPUSH(3, hq3, scq3)
        #undef QPUSH
        #undef PUSHC
    }
    if (lane == 0) {
        scnts[0 * NW + wid] = scq0; scnts[1 * NW + wid] = scq1;
        scnts[2 * NW + wid] = scq2; scnts[3 * NW + wid] = scq3;
    }
    __syncthreads();

    // ---- P4: compact + exact top-16 + loss (wave w -> query w) ----
    if (wid < NQ) {
        int l  = qg * NQ + wid;
        int bl = b * 256 + l;
        if (l == 255) {                    // its top-16 feeds only excluded row 0
            if (lane == 0) partial[bl] = 0.0f;
        } else {
            bool ovf = false;
            uint32_t pref = 0;
            #pragma unroll
            for (int j = 0; j < NW; ++j) {
                uint32_t c = scnts[wid * NW + j];
                ovf = ovf || (c > SEGSZ);
                uint32_t cc = min(c, (uint32_t)SEGSZ);
                if (lane < cc && pref + lane < UCAP)
                    comp64[wid * UCAP + pref + lane] =
                        seg64[(wid * NW + j) * SEGSZ + lane];
                pref += cc;
            }
            uint32_t U = pref;
            if (U > UCAP) ovf = true;

            float px1 = pred[(size_t)(bl + 1) * 8 + 0];
            float py1 = pred[(size_t)(bl + 1) * 8 + 1];
            const float* rb = ref + (size_t)b * 3 * HW;

            if (!ovf) {
                // candidate keys straight from LDS (no global gather)
                uint32_t kh0, kh1, kh2, kh3, kl0, kl1, kl2, kl3;
                #define LOADJ(jj, kh, kl)                                      \
                {                                                              \
                    uint32_t e = (jj) * 64 + lane;                             \
                    uint32_t h_ = 0xFFFFFFFFu, l_ = 0xFFFFFFFFu;               \
                    if (e < U) {                                               \
                        u64 v_ = comp64[wid * UCAP + e];                       \
                        h_ = (uint32_t)(v_ >> 32); l_ = (uint32_t)v_;          \
                    }                                                          \
                    kh = h_; kl = l_;                                          \
                }
                LOADJ(0, kh0, kl0) LOADJ(1, kh1, kl1) LOADJ(2, kh2, kl2) LOADJ(3, kh3, kl3)
                #undef LOADJ

                // stage A: smallest H with #{khi <= H} >= 16 (exact; padding
                // 0xFFFFFFFF can't distort since U >= 16 real finite keys)
                uint32_t lo = 0u, hi = 0xFFFFFFFFu;
                #pragma unroll 1
                for (int t = 0; t < 32; ++t) {
                    uint32_t mid = lo + ((hi - lo) >> 1);
                    int c = (int)__popcll(__ballot(kh0 <= mid))
                          + (int)__popcll(__ballot(kh1 <= mid))
                          + (int)__popcll(__ballot(kh2 <= mid))
                          + (int)__popcll(__ballot(kh3 <= mid));
                    if (c >= KK) hi = mid; else lo = mid + 1;
                }
                uint32_t Hh = hi;
                int c1 = (int)__popcll(__ballot(kh0 < Hh))
                       + (int)__popcll(__ballot(kh1 < Hh))
                       + (int)__popcll(__ballot(kh2 < Hh))
                       + (int)__popcll(__ballot(kh3 < Hh));
                u64 e0 = __ballot(kh0 == Hh), e1 = __ballot(kh1 == Hh);
                u64 e2 = __ballot(kh2 == Hh), e3 = __ballot(kh3 == Hh);
                int ec = (int)__popcll(e0) + (int)__popcll(e1)
                       + (int)__popcll(e2) + (int)__popcll(e3);
                int need = KK - c1;                    // 1..16; ec >= need by minimality
                uint32_t Lh = 0xFFFFFFFFu;
                if (ec != need) {
                    // float-tie among sims at the cut (rare): resolve by pidx
                    lo = 0u; hi = 0xFFFFFFFFu;
                    #pragma unroll 1
                    for (int t = 0; t < 32; ++t) {
                        uint32_t mid = lo + ((hi - lo) >> 1);
                        int c = (int)__popcll(e0 & __ballot(kl0 <= mid))
                              + (int)__popcll(e1 & __ballot(kl1 <= mid))
                              + (int)__popcll(e2 & __ballot(kl2 <= mid))
                              + (int)__popcll(e3 & __ballot(kl3 <= mid));
                        if (c >= need) hi = mid; else lo = mid + 1;
                    }
                    Lh = hi;
                }

                // lexicographic min of (ddbits, khi, klo) over the selected 16
                // == argmin over rank-ordered targets, first-min tie-break
                uint32_t bd = 0xFFFFFFFFu, bh = 0xFFFFFFFFu, bo = 0xFFFFFFFFu;
                #define SELJ(kh, kl)                                                    \
                {                                                                       \
                    bool sel = (kh < Hh) || (kh == Hh && kl <= Lh);                     \
                    if (sel) {                                                          \
                        uint32_t idxv = kl;                                             \
                        float tx = (float)(idxv % WW) / 192.0f;                         \
                        float ty = (float)(idxv / WW) / 192.0f;                         \
                        float ddx = __fsub_rn(px1, tx);                                 \
                        float ddy = __fsub_rn(py1, ty);                                 \
                        float dd = __fadd_rn(__fmul_rn(ddx, ddx), __fmul_rn(ddy, ddy)); \
                        uint32_t db = __float_as_uint(dd);   /* dd>=0: monotone */      \
                        bool lt = (db < bd) ||                                          \
                                  (db == bd && (kh < bh || (kh == bh && kl < bo)));     \
                        if (lt) { bd = db; bh = kh; bo = kl; }                          \
                    }                                                                   \
                }
                SELJ(kh0, kl0) SELJ(kh1, kl1) SELJ(kh2, kl2) SELJ(kh3, kl3)
                #undef SELJ
                #pragma unroll
                for (int off = 32; off >= 1; off >>= 1) {
                    uint32_t od = __shfl_xor(bd, off, 64);
                    uint32_t oh = __shfl_xor(bh, off, 64);
                    uint32_t oo = __shfl_xor(bo, off, 64);
                    bool lt = (od < bd) ||
                              (od == bd && (oh < bh || (oh == bh && oo < bo)));
                    if (lt) { bd = od; bh = oh; bo = oo; }
                }
                if (lane == 0) {
                    uint32_t idxv = bo;
                    float tx = (float)(idxv % WW) / 192.0f;
                    float ty = (float)(idxv / WW) / 192.0f;
                    float ex = __fsub_rn(px1, tx);
                    float ey = __fsub_rn(py1, ty);
                    partial[bl] = __fadd_rn(__fmul_rn(ex, ex), __fmul_rn(ey, ey));
                }
            } else {
                // safety net (P ~ 1e-20): exact full rescan for this query
                float4 pqv = spool[wid];
                float dmin = 3.4e38f, btx = 0.0f, bty = 0.0f;
                u64 kept16[KK];
                #pragma unroll
                for (int j = 0; j < KK; ++j) kept16[j] = ~0ull;
                const float4* pg = (const float4*)rb;
                #pragma unroll 1
                for (int st = lane; st < SITES; st += 64) {
                    float4 a0 = pg[st], a1 = pg[st + SITES], a2 = pg[st + 2 * SITES];
                    int base = st * 4;
                    #define FB(comp, ei)                                                \
                    {                                                                   \
                        float rs = exact_rsq(a0.comp, a1.comp, a2.comp);                \
                        float sx = exact_sim(a0.comp, a1.comp, a2.comp, rs,             \
                                             pqv.x, pqv.y, pqv.z, pqv.w);               \
                        u64 key = ((u64)fkey(sx) << 32) | (uint32_t)(base + (ei));      \
                        if (key < kept16[KK - 1]) insert64(kept16, key);                \
                    }
                    FB(x, 0) FB(y, 1) FB(z, 2) FB(w, 3)
                    #undef FB
                }
                #pragma unroll 1
                for (int rnd = 0; rnd < 16; ++rnd) {
                    u64 gm = wave_min_u64(kept16[0]);
                    if (kept16[0] == gm) {        // exactly one lane (unique keys)
                        #pragma unroll
                        for (int j = 0; j < KK - 1; ++j) kept16[j] = kept16[j + 1];
                        kept16[KK - 1] = ~0ull;
                    }
                    LOSS_STEP(gm)
                }
                if (lane == 0) {
                    float ex = __fsub_rn(px1, btx);
                    float ey = __fsub_rn(py1, bty);
                    partial[bl] = __fadd_rn(__fmul_rn(ex, ex), __fmul_rn(ey, ey));
                }
            }
        }
    }
}

// ---------- reduce 2048 partials -> mean ----------
__global__ __launch_bounds__(256) void reduce_kernel(const float* __restrict__ partial,
                                                     float* __restrict__ out) {
    __shared__ double sred[256];
    double a = 0.0;
    #pragma unroll
    for (int i = 0; i < 8; ++i) a += (double)partial[i * 256 + threadIdx.x];
    sred[threadIdx.x] = a;
    __syncthreads();
    for (int s = 128; s > 0; s >>= 1) {
        if (threadIdx.x < s) sred[threadIdx.x] += sred[threadIdx.x + s];
        __syncthreads();
    }
    if (threadIdx.x == 0) out[0] = (float)(sred[0] / 2040.0);
}

// ---------- launch ----------
extern "C" void kernel_launch(void* const* d_in, const int* in_sizes, int n_in,
                              void* d_out, int out_size, void* d_ws, size_t ws_size,
                              hipStream_t stream) {
    const float* pred = (const float*)d_in[0];   // (8,256,8) f32
    const float* ref  = (const float*)d_in[1];   // (8,3,192,192) f32
    float* out = (float*)d_out;

    float* partial = (float*)d_ws;               // 2048 floats, fully overwritten

    fused_kernel <<<512, 1024, 0, stream>>>(pred, ref, partial);
    reduce_kernel<<<  1,  256, 0, stream>>>(partial, out);
}

// Round 8
// 86.579 us; speedup vs baseline: 1.6615x; 1.6602x over previous
//
#include <hip/hip_runtime.h>
#include <stdint.h>

#define BS 8
#define HH 192
#define WW 192
#define HW (HH*WW)          /* 36864 pixels per plane */
#define KK 16
#define SITES 9216          /* float4 sites per plane */
#define NQ 4                /* queries per block */
#define NW 16               /* waves per block */
#define SEGSZ 32            /* per-(query,wave) segment capacity; E ~ 2.25 */
#define UCAP 256            /* per-query merged candidate cap (4 keys/lane) */
#define PAD_FILT 4e-5f      /* filter safety: fma-vs-exact error ~1e-6 */

typedef unsigned long long u64;

// ---------- helpers ----------

__device__ __forceinline__ uint32_t fkey(float f) {
    uint32_t u = __float_as_uint(f);
    uint32_t mask = (uint32_t)((int32_t)u >> 31) | 0x80000000u;
    return u ^ mask;
}
__device__ __forceinline__ float inv_fkey(uint32_t v) {
    uint32_t u = (v & 0x80000000u) ? (v ^ 0x80000000u) : ~v;
    return __uint_as_float(u);
}

__device__ __forceinline__ u64 umin64(u64 a, u64 b) { return a < b ? a : b; }

__device__ __forceinline__ uint32_t mbcnt64(u64 m) {
    return __builtin_amdgcn_mbcnt_hi((uint32_t)(m >> 32),
            __builtin_amdgcn_mbcnt_lo((uint32_t)m, 0));
}

__device__ __forceinline__ u64 wave_min_u64(u64 v) {   // fallback path only
    #pragma unroll
    for (int off = 32; off >= 1; off >>= 1) {
        uint32_t lo = (uint32_t)v, hi = (uint32_t)(v >> 32);
        lo = __shfl_xor(lo, off, 64);
        hi = __shfl_xor(hi, off, 64);
        u64 o = ((u64)hi << 32) | lo;
        v = umin64(v, o);
    }
    return v;
}

// sorted ascending insertion, 16 deep (fallback path only)
__device__ __forceinline__ void insert64(u64 (&kept)[KK], u64 key) {
    #pragma unroll
    for (int j = KK - 1; j >= 1; --j) {
        u64 a = kept[j - 1];
        u64 mn = umin64(kept[j], key);
        kept[j] = (key < a) ? a : mn;
    }
    kept[0] = umin64(kept[0], key);
}

// exact (reference-rounded) similarity pieces — bit-identical to validated kernel
__device__ __forceinline__ float exact_rsq(float a, float b, float c) {
    return __fadd_rn(__fadd_rn(__fmul_rn(a, a), __fmul_rn(b, b)), __fmul_rn(c, c));
}
__device__ __forceinline__ float exact_sim(float c0, float c1, float c2, float rsq,
                                           float qx_, float qy_, float qz_, float qw_) {
    float cr = __fadd_rn(__fadd_rn(__fmul_rn(c0, qx_), __fmul_rn(c1, qy_)), __fmul_rn(c2, qz_));
    return __fadd_rn(__fsub_rn(rsq, __fmul_rn(2.0f, cr)), qw_);
}

// loss-term tracking (fallback path): strict < keeps first (lowest-rank) min
#define LOSS_STEP(gmv)                                                   \
{                                                                        \
    uint32_t idxv = (uint32_t)(gmv);                                     \
    float tx = (float)(idxv % WW) / 192.0f;                              \
    float ty = (float)(idxv / WW) / 192.0f;                              \
    float ddx = __fsub_rn(px1, tx);                                      \
    float ddy = __fsub_rn(py1, ty);                                      \
    float dd = __fadd_rn(__fmul_rn(ddx, ddx), __fmul_rn(ddy, ddy));      \
    if (dd < dmin) { dmin = dd; btx = tx; bty = ty; }                    \
}

// ---------- fused kernel: block = (image, 4 queries), 1024 threads ----------
// P0: pooled/psq per query (exact, verbatim reference rounding)
// P1: sample sites 0..4095 once, shared across 4 queries; per-thread per-query
//     MAX d (sound threshold: 16th-largest of 1024 disjoint group-maxima <=
//     sample 16th-best <= image 16th-best); keys -> LDS
// P2: waves 0..3 — 20-step ballot-count binsearch; hi stays a sound upper
//     bound at every step; h = -d(hi) - PAD
// P3: all 16 waves scan the full image once; shared -0.5*rsq; passing PIXEL
//     INDEX (u32) -> private per-(query,wave) LDS segment (ballot+mbcnt, no
//     atomics). u32 push keeps P3 live set ~50 VGPR: rounds 6-7 proved the
//     exact-sim u64 push exceeds the 64-reg budget of launch_bounds(1024,8)
//     and produces 68-111 MB/dispatch of scratch spill traffic.
// P4: waves 0..3 — compact indices, divergent gather (3 ch/px, ~36 px/query,
//     L2-resident: ~0.5us), exact sims; exact top-16 via stage-A ballot
//     binsearch (+rare stage-B on float-ties); lexicographic (dd,key) argmin
//     == reference rank-order with first-min tie-break
__global__ __launch_bounds__(1024, 8) void fused_kernel(const float* __restrict__ pred,
                                                        const float* __restrict__ ref,
                                                        float* __restrict__ partial) {
    __shared__ uint32_t mxbuf[4096];          // 16 KB: P1 keys, then P3 segments (8 KB used)
    __shared__ uint32_t compactb[NQ * UCAP];  // 4 KB
    __shared__ uint32_t scnts[NQ * NW];
    __shared__ float4 spool[NQ];
    __shared__ float shq[NQ];

    int tid  = threadIdx.x;
    int lane = tid & 63;
    int wid  = tid >> 6;              // 0..15
    int b  = blockIdx.x & 7;          // XCD swizzle: image b -> XCD b
    int qg = blockIdx.x >> 3;         // 0..63

    // ---- P0 ----
    if (tid < NQ) {
        int l = qg * NQ + tid;
        int i = l * BS + b;           // scrambled flat grid row
        int b2 = i >> 8, l2 = i & 255;
        const float* pr = pred + ((b2 * 256 + l2) * 8);
        float x = pr[0], y = pr[1];
        float fx = rintf(__fsub_rn(__fmul_rn(x, 192.0f), 0.5f));
        float fy = rintf(__fsub_rn(__fmul_rn(y, 192.0f), 0.5f));
        int ix = (int)fx, iy = (int)fy;
        int inb = (ix >= 0 && ix < WW && iy >= 0 && iy < HH) ? 1 : 0;
        int ixc = min(max(ix, 0), WW - 1);
        int iyc = min(max(iy, 0), HH - 1);
        float m = (float)inb;
        const float* img = ref + b * 3 * HW + iyc * WW + ixc;
        float p0 = __fmul_rn(img[0], m);
        float p1 = __fmul_rn(img[HW], m);
        float p2 = __fmul_rn(img[2 * HW], m);
        float psq = __fadd_rn(__fadd_rn(__fmul_rn(p0, p0), __fmul_rn(p1, p1)),
                              __fmul_rn(p2, p2));
        spool[tid] = make_float4(p0, p1, p2, psq);
    }
    __syncthreads();

    const float4* p0g = (const float4*)(ref + (size_t)b * 3 * HW);
    float qx[NQ], qy[NQ], qz[NQ];
    #pragma unroll
    for (int q = 0; q < NQ; ++q) {
        float4 s = spool[q];
        qx[q] = s.x; qy[q] = s.y; qz[q] = s.z;
    }

    // ---- P1: shared sampling, per-thread per-query max (no prefetch) ----
    float md0 = -3.4e38f, md1 = -3.4e38f, md2 = -3.4e38f, md3 = -3.4e38f;
    #pragma unroll 1
    for (int it = 0; it < 4; ++it) {
        int site = tid + it * 1024;
        float4 a0 = p0g[site], a1 = p0g[site + SITES], a2 = p0g[site + 2 * SITES];
        #define SAMP(comp)                                                              \
        {                                                                               \
            float nr = -0.5f * fmaf(a2.comp, a2.comp, fmaf(a1.comp, a1.comp,            \
                              a0.comp * a0.comp));                                      \
            float d0_ = fmaf(a2.comp, qz[0], fmaf(a1.comp, qy[0], fmaf(a0.comp, qx[0], nr))); \
            float d1_ = fmaf(a2.comp, qz[1], fmaf(a1.comp, qy[1], fmaf(a0.comp, qx[1], nr))); \
            float d2_ = fmaf(a2.comp, qz[2], fmaf(a1.comp, qy[2], fmaf(a0.comp, qx[2], nr))); \
            float d3_ = fmaf(a2.comp, qz[3], fmaf(a1.comp, qy[3], fmaf(a0.comp, qx[3], nr))); \
            md0 = fmaxf(md0, d0_); md1 = fmaxf(md1, d1_);                               \
            md2 = fmaxf(md2, d2_); md3 = fmaxf(md3, d3_);                               \
        }
        SAMP(x) SAMP(y) SAMP(z) SAMP(w)
        #undef SAMP
    }
    mxbuf[0 * 1024 + tid] = fkey(-md0);
    mxbuf[1 * 1024 + tid] = fkey(-md1);
    mxbuf[2 * 1024 + tid] = fkey(-md2);
    mxbuf[3 * 1024 + tid] = fkey(-md3);
    __syncthreads();

    // ---- P2: per-query threshold (wave w -> query w), 20-step binsearch ----
    if (wid < NQ) {
        uint32_t v[16];
        #pragma unroll
        for (int j = 0; j < 16; ++j) v[j] = mxbuf[wid * 1024 + lane + 64 * j];
        uint32_t lo = 0u, hi = 0xFFFFFFFFu;
        #pragma unroll 1
        for (int t = 0; t < 20; ++t) {
            uint32_t mid = lo + ((hi - lo) >> 1);
            int c = 0;
            #pragma unroll
            for (int j = 0; j < 16; ++j) c += (int)__popcll(__ballot(v[j] <= mid));
            if (c >= KK) hi = mid; else lo = mid + 1;
        }
        float hval = -inv_fkey(hi) - PAD_FILT;
        if (qg == 63 && wid == 3) hval = 3.0e38f;   // l==255: never pass
        if (lane == 0) shq[wid] = hval;
    }
    __syncthreads();                  // also fences mxbuf reuse as segments

    // ---- P3: full-image scan, u32 index push into private segments ----
    float hq0 = shq[0], hq1 = shq[1], hq2 = shq[2], hq3 = shq[3];
    uint32_t scq0 = 0, scq1 = 0, scq2 = 0, scq3 = 0;

    #pragma unroll 1
    for (int it = 0; it < 9; ++it) {           // 9*1024 = 9216 sites
        int site = tid + it * 1024;
        float4 a0 = p0g[site], a1 = p0g[site + SITES], a2 = p0g[site + 2 * SITES];
        int base = site * 4;

        float nrx = -0.5f * fmaf(a2.x, a2.x, fmaf(a1.x, a1.x, a0.x * a0.x));
        float nry = -0.5f * fmaf(a2.y, a2.y, fmaf(a1.y, a1.y, a0.y * a0.y));
        float nrz = -0.5f * fmaf(a2.z, a2.z, fmaf(a1.z, a1.z, a0.z * a0.z));
        float nrw = -0.5f * fmaf(a2.w, a2.w, fmaf(a1.w, a1.w, a0.w * a0.w));

        #define QPUSH(qi, hqv, scq)                                                     \
        {                                                                               \
            float hqv_ = hqv;                                                           \
            float d0 = fmaf(a2.x, qz[qi], fmaf(a1.x, qy[qi], fmaf(a0.x, qx[qi], nrx))); \
            float d1 = fmaf(a2.y, qz[qi], fmaf(a1.y, qy[qi], fmaf(a0.y, qx[qi], nry))); \
            float d2 = fmaf(a2.z, qz[qi], fmaf(a1.z, qy[qi], fmaf(a0.z, qx[qi], nrz))); \
            float d3 = fmaf(a2.w, qz[qi], fmaf(a1.w, qy[qi], fmaf(a0.w, qx[qi], nrw))); \
            u64 m0 = __ballot(d0 >= hqv_);                                              \
            u64 m1 = __ballot(d1 >= hqv_);                                              \
            u64 m2 = __ballot(d2 >= hqv_);                                              \
            u64 m3 = __ballot(d3 >= hqv_);                                              \
            if (m0 | m1 | m2 | m3) {          /* wave-uniform scalar branch */          \
                uint32_t sb = ((qi) * NW + wid) * SEGSZ;                                \
                uint32_t c = scq;                                                       \
                if (d0 >= hqv_) { uint32_t s_ = c + mbcnt64(m0);                        \
                                  if (s_ < SEGSZ) mxbuf[sb + s_] = (uint32_t)(base + 0); } \
                c += (uint32_t)__popcll(m0);                                            \
                if (d1 >= hqv_) { uint32_t s_ = c + mbcnt64(m1);                        \
                                  if (s_ < SEGSZ) mxbuf[sb + s_] = (uint32_t)(base + 1); } \
                c += (uint32_t)__popcll(m1);                                            \
                if (d2 >= hqv_) { uint32_t s_ = c + mbcnt64(m2);                        \
                                  if (s_ < SEGSZ) mxbuf[sb + s_] = (uint32_t)(base + 2); } \
                c += (uint32_t)__popcll(m2);                                            \
                if (d3 >= hqv_) { uint32_t s_ = c + mbcnt64(m3);                        \
                                  if (s_ < SEGSZ) mxbuf[sb + s_] = (uint32_t)(base + 3); } \
                c += (uint32_t)__popcll(m3);                                            \
                scq = c;                                                                \
            }                                                                           \
        }
        QPUSH(0, hq0, scq0) QPUSH(1, hq1, scq1) QPUSH(2, hq2, scq2) QPUSH(3, hq3, scq3)
        #undef QPUSH
    }
    if (lane == 0) {
        scnts[0 * NW + wid] = scq0; scnts[1 * NW + wid] = scq1;
        scnts[2 * NW + wid] = scq2; scnts[3 * NW + wid] = scq3;
    }
    __syncthreads();

    // ---- P4: compact + gather + exact top-16 + loss (wave w -> query w) ----
    if (wid < NQ) {
        int l  = qg * NQ + wid;
        int bl = b * 256 + l;
        if (l == 255) {                    // its top-16 feeds only excluded row 0
            if (lane == 0) partial[bl] = 0.0f;
        } else {
            bool ovf = false;
            uint32_t pref = 0;
            #pragma unroll
            for (int j = 0; j < NW; ++j) {
                uint32_t c = scnts[wid * NW + j];
                ovf = ovf || (c > SEGSZ);
                uint32_t cc = min(c, (uint32_t)SEGSZ);
                if (lane < cc && pref + lane < UCAP)
                    compactb[wid * UCAP + pref + lane] =
                        mxbuf[(wid * NW + j) * SEGSZ + lane];
                pref += cc;
            }
            uint32_t U = pref;
            if (U > UCAP) ovf = true;

            float px1 = pred[(size_t)(bl + 1) * 8 + 0];
            float py1 = pred[(size_t)(bl + 1) * 8 + 1];
            float4 pqv = spool[wid];
            const float* rb = ref + (size_t)b * 3 * HW;

            if (!ovf) {
                // gather candidates (<=4/lane), exact sims, (simkey,pidx)
                uint32_t kh0, kh1, kh2, kh3, kl0, kl1, kl2, kl3;
                #define LOADJ(jj, kh, kl)                                               \
                {                                                                       \
                    uint32_t e = (jj) * 64 + lane;                                      \
                    uint32_t h_ = 0xFFFFFFFFu, l_ = 0xFFFFFFFFu;                        \
                    if (e < U) {                                                        \
                        uint32_t pidx = compactb[wid * UCAP + e];                       \
                        float c0v = rb[pidx], c1v = rb[pidx + HW], c2v = rb[pidx + 2 * HW]; \
                        float rs = exact_rsq(c0v, c1v, c2v);                            \
                        float sx = exact_sim(c0v, c1v, c2v, rs,                         \
                                             pqv.x, pqv.y, pqv.z, pqv.w);               \
                        h_ = fkey(sx); l_ = pidx;                                       \
                    }                                                                   \
                    kh = h_; kl = l_;                                                   \
                }
                LOADJ(0, kh0, kl0) LOADJ(1, kh1, kl1) LOADJ(2, kh2, kl2) LOADJ(3, kh3, kl3)
                #undef LOADJ

                // stage A: smallest H with #{khi <= H} >= 16 (exact; padding
                // 0xFFFFFFFF can't distort since U >= 16 real finite keys)
                uint32_t lo = 0u, hi = 0xFFFFFFFFu;
                #pragma unroll 1
                for (int t = 0; t < 32; ++t) {
                    uint32_t mid = lo + ((hi - lo) >> 1);
                    int c = (int)__popcll(__ballot(kh0 <= mid))
                          + (int)__popcll(__ballot(kh1 <= mid))
                          + (int)__popcll(__ballot(kh2 <= mid))
                          + (int)__popcll(__ballot(kh3 <= mid));
                    if (c >= KK) hi = mid; else lo = mid + 1;
                }
                uint32_t Hh = hi;
                int c1 = (int)__popcll(__ballot(kh0 < Hh))
                       + (int)__popcll(__ballot(kh1 < Hh))
                       + (int)__popcll(__ballot(kh2 < Hh))
                       + (int)__popcll(__ballot(kh3 < Hh));
                u64 e0 = __ballot(kh0 == Hh), e1 = __ballot(kh1 == Hh);
                u64 e2 = __ballot(kh2 == Hh), e3 = __ballot(kh3 == Hh);
                int ec = (int)__popcll(e0) + (int)__popcll(e1)
                       + (int)__popcll(e2) + (int)__popcll(e3);
                int need = KK - c1;                    // 1..16; ec >= need by minimality
                uint32_t Lh = 0xFFFFFFFFu;
                if (ec != need) {
                    // float-tie among sims at the cut (rare): resolve by pidx
                    lo = 0u; hi = 0xFFFFFFFFu;
                    #pragma unroll 1
                    for (int t = 0; t < 32; ++t) {
                        uint32_t mid = lo + ((hi - lo) >> 1);
                        int c = (int)__popcll(e0 & __ballot(kl0 <= mid))
                              + (int)__popcll(e1 & __ballot(kl1 <= mid))
                              + (int)__popcll(e2 & __ballot(kl2 <= mid))
                              + (int)__popcll(e3 & __ballot(kl3 <= mid));
                        if (c >= need) hi = mid; else lo = mid + 1;
                    }
                    Lh = hi;
                }

                // lexicographic min of (ddbits, khi, klo) over the selected 16
                // == argmin over rank-ordered targets, first-min tie-break
                uint32_t bd = 0xFFFFFFFFu, bh = 0xFFFFFFFFu, bo = 0xFFFFFFFFu;
                #define SELJ(kh, kl)                                                    \
                {                                                                       \
                    bool sel = (kh < Hh) || (kh == Hh && kl <= Lh);                     \
                    if (sel) {                                                          \
                        uint32_t idxv = kl;                                             \
                        float tx = (float)(idxv % WW) / 192.0f;                         \
                        float ty = (float)(idxv / WW) / 192.0f;                         \
                        float ddx = __fsub_rn(px1, tx);                                 \
                        float ddy = __fsub_rn(py1, ty);                                 \
                        float dd = __fadd_rn(__fmul_rn(ddx, ddx), __fmul_rn(ddy, ddy)); \
                        uint32_t db = __float_as_uint(dd);   /* dd>=0: monotone */      \
                        bool lt = (db < bd) ||                                          \
                                  (db == bd && (kh < bh || (kh == bh && kl < bo)));     \
                        if (lt) { bd = db; bh = kh; bo = kl; }                          \
                    }                                                                   \
                }
                SELJ(kh0, kl0) SELJ(kh1, kl1) SELJ(kh2, kl2) SELJ(kh3, kl3)
                #undef SELJ
                #pragma unroll
                for (int off = 32; off >= 1; off >>= 1) {
                    uint32_t od = __shfl_xor(bd, off, 64);
                    uint32_t oh = __shfl_xor(bh, off, 64);
                    uint32_t oo = __shfl_xor(bo, off, 64);
                    bool lt = (od < bd) ||
                              (od == bd && (oh < bh || (oh == bh && oo < bo)));
                    if (lt) { bd = od; bh = oh; bo = oo; }
                }
                if (lane == 0) {
                    uint32_t idxv = bo;
                    float tx = (float)(idxv % WW) / 192.0f;
                    float ty = (float)(idxv / WW) / 192.0f;
                    float ex = __fsub_rn(px1, tx);
                    float ey = __fsub_rn(py1, ty);
                    partial[bl] = __fadd_rn(__fmul_rn(ex, ex), __fmul_rn(ey, ey));
                }
            } else {
                // safety net (P ~ 1e-20): exact full rescan for this query
                float dmin = 3.4e38f, btx = 0.0f, bty = 0.0f;
                u64 kept16[KK];
                #pragma unroll
                for (int j = 0; j < KK; ++j) kept16[j] = ~0ull;
                const float4* pg = (const float4*)rb;
                #pragma unroll 1
                for (int st = lane; st < SITES; st += 64) {
                    float4 a0 = pg[st], a1 = pg[st + SITES], a2 = pg[st + 2 * SITES];
                    int base = st * 4;
                    #define FB(comp, ei)                                                \
                    {                                                                   \
                        float rs = exact_rsq(a0.comp, a1.comp, a2.comp);                \
                        float sx = exact_sim(a0.comp, a1.comp, a2.comp, rs,             \
                                             pqv.x, pqv.y, pqv.z, pqv.w);               \
                        u64 key = ((u64)fkey(sx) << 32) | (uint32_t)(base + (ei));      \
                        if (key < kept16[KK - 1]) insert64(kept16, key);                \
                    }
                    FB(x, 0) FB(y, 1) FB(z, 2) FB(w, 3)
                    #undef FB
                }
                #pragma unroll 1
                for (int rnd = 0; rnd < 16; ++rnd) {
                    u64 gm = wave_min_u64(kept16[0]);
                    if (kept16[0] == gm) {        // exactly one lane (unique keys)
                        #pragma unroll
                        for (int j = 0; j < KK - 1; ++j) kept16[j] = kept16[j + 1];
                        kept16[KK - 1] = ~0ull;
                    }
                    LOSS_STEP(gm)
                }
                if (lane == 0) {
                    float ex = __fsub_rn(px1, btx);
                    float ey = __fsub_rn(py1, bty);
                    partial[bl] = __fadd_rn(__fmul_rn(ex, ex), __fmul_rn(ey, ey));
                }
            }
        }
    }
}

// ---------- reduce 2048 partials -> mean ----------
__global__ __launch_bounds__(256) void reduce_kernel(const float* __restrict__ partial,
                                                     float* __restrict__ out) {
    __shared__ double sred[256];
    double a = 0.0;
    #pragma unroll
    for (int i = 0; i < 8; ++i) a += (double)partial[i * 256 + threadIdx.x];
    sred[threadIdx.x] = a;
    __syncthreads();
    for (int s = 128; s > 0; s >>= 1) {
        if (threadIdx.x < s) sred[threadIdx.x] += sred[threadIdx.x + s];
        __syncthreads();
    }
    if (threadIdx.x == 0) out[0] = (float)(sred[0] / 2040.0);
}

// ---------- launch ----------
extern "C" void kernel_launch(void* const* d_in, const int* in_sizes, int n_in,
                              void* d_out, int out_size, void* d_ws, size_t ws_size,
                              hipStream_t stream) {
    const float* pred = (const float*)d_in[0];   // (8,256,8) f32
    const float* ref  = (const float*)d_in[1];   // (8,3,192,192) f32
    float* out = (float*)d_out;

    float* partial = (float*)d_ws;               // 2048 floats, fully overwritten

    fused_kernel <<<512, 1024, 0, stream>>>(pred, ref, partial);
    reduce_kernel<<<  1,  256, 0, stream>>>(partial, out);
}

// Round 10
// 85.671 us; speedup vs baseline: 1.6792x; 1.0106x over previous
//
#include <hip/hip_runtime.h>
#include <stdint.h>

#define BS 8
#define HH 192
#define WW 192
#define HW (HH*WW)          /* 36864 pixels per plane */
#define KK 16
#define SITES 9216          /* float4 sites per plane */
#define NQ 4                /* queries per block */
#define NW 16               /* waves per block */
#define SEGSZ 32            /* per-(query,wave) segment capacity; E ~ 4.5 */
#define UCAP 256            /* per-query merged candidate cap (4 keys/lane) */
#define PAD_FILT 4e-5f      /* filter safety: fma-vs-exact error ~1e-6 */

typedef unsigned long long u64;

// ---------- helpers ----------

__device__ __forceinline__ uint32_t fkey(float f) {
    uint32_t u = __float_as_uint(f);
    uint32_t mask = (uint32_t)((int32_t)u >> 31) | 0x80000000u;
    return u ^ mask;
}
__device__ __forceinline__ float inv_fkey(uint32_t v) {
    uint32_t u = (v & 0x80000000u) ? (v ^ 0x80000000u) : ~v;
    return __uint_as_float(u);
}

__device__ __forceinline__ u64 umin64(u64 a, u64 b) { return a < b ? a : b; }

__device__ __forceinline__ uint32_t mbcnt64(u64 m) {
    return __builtin_amdgcn_mbcnt_hi((uint32_t)(m >> 32),
            __builtin_amdgcn_mbcnt_lo((uint32_t)m, 0));
}

// wave-uniform float -> SGPR broadcast. MUST bit-cast: the builtin is
// int-typed, and a bare float argument does a silent float->int VALUE
// conversion (round-9 failure: thresholds truncated to 0, padding index
// 0xFFFFFFFF decoded to ty=116508 -> absmax 1.36e10 = 116508^2).
__device__ __forceinline__ float rfl(float v) {
    return __uint_as_float((uint32_t)__builtin_amdgcn_readfirstlane(
                               (int)__float_as_uint(v)));
}

__device__ __forceinline__ u64 wave_min_u64(u64 v) {   // fallback path only
    #pragma unroll
    for (int off = 32; off >= 1; off >>= 1) {
        uint32_t lo = (uint32_t)v, hi = (uint32_t)(v >> 32);
        lo = __shfl_xor(lo, off, 64);
        hi = __shfl_xor(hi, off, 64);
        u64 o = ((u64)hi << 32) | lo;
        v = umin64(v, o);
    }
    return v;
}

// sorted ascending insertion, 16 deep (fallback path only)
__device__ __forceinline__ void insert64(u64 (&kept)[KK], u64 key) {
    #pragma unroll
    for (int j = KK - 1; j >= 1; --j) {
        u64 a = kept[j - 1];
        u64 mn = umin64(kept[j], key);
        kept[j] = (key < a) ? a : mn;
    }
    kept[0] = umin64(kept[0], key);
}

// exact (reference-rounded) similarity pieces — bit-identical to validated kernel
__device__ __forceinline__ float exact_rsq(float a, float b, float c) {
    return __fadd_rn(__fadd_rn(__fmul_rn(a, a), __fmul_rn(b, b)), __fmul_rn(c, c));
}
__device__ __forceinline__ float exact_sim(float c0, float c1, float c2, float rsq,
                                           float qx_, float qy_, float qz_, float qw_) {
    float cr = __fadd_rn(__fadd_rn(__fmul_rn(c0, qx_), __fmul_rn(c1, qy_)), __fmul_rn(c2, qz_));
    return __fadd_rn(__fsub_rn(rsq, __fmul_rn(2.0f, cr)), qw_);
}

// loss-term tracking (fallback path): strict < keeps first (lowest-rank) min
#define LOSS_STEP(gmv)                                                   \
{                                                                        \
    uint32_t idxv = (uint32_t)(gmv);                                     \
    float tx = (float)(idxv % WW) / 192.0f;                              \
    float ty = (float)(idxv / WW) / 192.0f;                              \
    float ddx = __fsub_rn(px1, tx);                                      \
    float ddy = __fsub_rn(py1, ty);                                      \
    float dd = __fadd_rn(__fmul_rn(ddx, ddx), __fmul_rn(ddy, ddy));      \
    if (dd < dmin) { dmin = dd; btx = tx; bty = ty; }                    \
}

// ---------- fused kernel: block = (image, 4 queries), 1024 threads ----------
// Round-8 structure + v9 perf deltas (SGPR param hoist via CORRECT bitcast
// readfirstlane, P3 1-deep prefetch, P1 halved to 2048 shared sites).
__global__ __launch_bounds__(1024, 8) void fused_kernel(const float* __restrict__ pred,
                                                        const float* __restrict__ ref,
                                                        float* __restrict__ partial) {
    __shared__ uint32_t mxbuf[4096];          // 16 KB: P1 keys, then P3 segments
    __shared__ uint32_t compactb[NQ * UCAP];  // 4 KB
    __shared__ uint32_t scnts[NQ * NW];
    __shared__ float4 spool[NQ];
    __shared__ float shq[NQ];

    int tid  = threadIdx.x;
    int lane = tid & 63;
    int wid  = tid >> 6;              // 0..15
    int b  = blockIdx.x & 7;          // XCD swizzle: image b -> XCD b
    int qg = blockIdx.x >> 3;         // 0..63

    // ---- P0 ----
    if (tid < NQ) {
        int l = qg * NQ + tid;
        int i = l * BS + b;           // scrambled flat grid row
        int b2 = i >> 8, l2 = i & 255;
        const float* pr = pred + ((b2 * 256 + l2) * 8);
        float x = pr[0], y = pr[1];
        float fx = rintf(__fsub_rn(__fmul_rn(x, 192.0f), 0.5f));
        float fy = rintf(__fsub_rn(__fmul_rn(y, 192.0f), 0.5f));
        int ix = (int)fx, iy = (int)fy;
        int inb = (ix >= 0 && ix < WW && iy >= 0 && iy < HH) ? 1 : 0;
        int ixc = min(max(ix, 0), WW - 1);
        int iyc = min(max(iy, 0), HH - 1);
        float m = (float)inb;
        const float* img = ref + b * 3 * HW + iyc * WW + ixc;
        float p0 = __fmul_rn(img[0], m);
        float p1 = __fmul_rn(img[HW], m);
        float p2 = __fmul_rn(img[2 * HW], m);
        float psq = __fadd_rn(__fadd_rn(__fmul_rn(p0, p0), __fmul_rn(p1, p1)),
                              __fmul_rn(p2, p2));
        spool[tid] = make_float4(p0, p1, p2, psq);
    }
    __syncthreads();

    const float4* p0g = (const float4*)(ref + (size_t)b * 3 * HW);
    // wave-uniform query params -> SGPRs (bitcast broadcast)
    float qx[NQ], qy[NQ], qz[NQ];
    #pragma unroll
    for (int q = 0; q < NQ; ++q) {
        float4 s = spool[q];
        qx[q] = rfl(s.x); qy[q] = rfl(s.y); qz[q] = rfl(s.z);
    }

    // ---- P1: shared sampling (2048 sites), per-thread per-query max ----
    float md0, md1, md2, md3;
    {
        float4 b0 = p0g[tid], b1 = p0g[tid + SITES], b2 = p0g[tid + 2 * SITES];
        float4 c0 = p0g[tid + 1024], c1 = p0g[tid + 1024 + SITES],
               c2 = p0g[tid + 1024 + 2 * SITES];
        md0 = md1 = md2 = md3 = -3.4e38f;
        #define SAMP(A0, A1, A2, comp)                                                  \
        {                                                                               \
            float nr = -0.5f * fmaf(A2.comp, A2.comp, fmaf(A1.comp, A1.comp,            \
                              A0.comp * A0.comp));                                      \
            float d0_ = fmaf(A2.comp, qz[0], fmaf(A1.comp, qy[0], fmaf(A0.comp, qx[0], nr))); \
            float d1_ = fmaf(A2.comp, qz[1], fmaf(A1.comp, qy[1], fmaf(A0.comp, qx[1], nr))); \
            float d2_ = fmaf(A2.comp, qz[2], fmaf(A1.comp, qy[2], fmaf(A0.comp, qx[2], nr))); \
            float d3_ = fmaf(A2.comp, qz[3], fmaf(A1.comp, qy[3], fmaf(A0.comp, qx[3], nr))); \
            md0 = fmaxf(md0, d0_); md1 = fmaxf(md1, d1_);                               \
            md2 = fmaxf(md2, d2_); md3 = fmaxf(md3, d3_);                               \
        }
        SAMP(b0, b1, b2, x) SAMP(b0, b1, b2, y) SAMP(b0, b1, b2, z) SAMP(b0, b1, b2, w)
        SAMP(c0, c1, c2, x) SAMP(c0, c1, c2, y) SAMP(c0, c1, c2, z) SAMP(c0, c1, c2, w)
        #undef SAMP
    }
    mxbuf[0 * 1024 + tid] = fkey(-md0);
    mxbuf[1 * 1024 + tid] = fkey(-md1);
    mxbuf[2 * 1024 + tid] = fkey(-md2);
    mxbuf[3 * 1024 + tid] = fkey(-md3);
    __syncthreads();

    // ---- P2: per-query threshold (wave w -> query w), 20-step binsearch ----
    if (wid < NQ) {
        uint32_t v[16];
        #pragma unroll
        for (int j = 0; j < 16; ++j) v[j] = mxbuf[wid * 1024 + lane + 64 * j];
        uint32_t lo = 0u, hi = 0xFFFFFFFFu;
        #pragma unroll 1
        for (int t = 0; t < 20; ++t) {
            uint32_t mid = lo + ((hi - lo) >> 1);
            int c = 0;
            #pragma unroll
            for (int j = 0; j < 16; ++j) c += (int)__popcll(__ballot(v[j] <= mid));
            if (c >= KK) hi = mid; else lo = mid + 1;
        }
        float hval = -inv_fkey(hi) - PAD_FILT;
        if (qg == 63 && wid == 3) hval = 3.0e38f;   // l==255: never pass
        if (lane == 0) shq[wid] = hval;
    }
    __syncthreads();                  // also fences mxbuf reuse as segments

    // ---- P3: full-image scan, 1-deep prefetch, u32 index push ----
    float hq0 = rfl(shq[0]), hq1 = rfl(shq[1]), hq2 = rfl(shq[2]), hq3 = rfl(shq[3]);
    uint32_t scq0 = 0, scq1 = 0, scq2 = 0, scq3 = 0;

    int site = tid;
    float4 n0 = p0g[site], n1 = p0g[site + SITES], n2 = p0g[site + 2 * SITES];

    #pragma unroll 1
    for (int it = 0; it < 9; ++it) {           // 9*1024 = 9216 sites
        float4 a0 = n0, a1 = n1, a2 = n2;
        int sn = (it < 8) ? (site + 1024) : site;   // clamped last prefetch
        n0 = p0g[sn]; n1 = p0g[sn + SITES]; n2 = p0g[sn + 2 * SITES];
        int base = site * 4;

        float nrx = -0.5f * fmaf(a2.x, a2.x, fmaf(a1.x, a1.x, a0.x * a0.x));
        float nry = -0.5f * fmaf(a2.y, a2.y, fmaf(a1.y, a1.y, a0.y * a0.y));
        float nrz = -0.5f * fmaf(a2.z, a2.z, fmaf(a1.z, a1.z, a0.z * a0.z));
        float nrw = -0.5f * fmaf(a2.w, a2.w, fmaf(a1.w, a1.w, a0.w * a0.w));

        #define QPUSH(qi, hqv, scq)                                                     \
        {                                                                               \
            float d0 = fmaf(a2.x, qz[qi], fmaf(a1.x, qy[qi], fmaf(a0.x, qx[qi], nrx))); \
            float d1 = fmaf(a2.y, qz[qi], fmaf(a1.y, qy[qi], fmaf(a0.y, qx[qi], nry))); \
            float d2 = fmaf(a2.z, qz[qi], fmaf(a1.z, qy[qi], fmaf(a0.z, qx[qi], nrz))); \
            float d3 = fmaf(a2.w, qz[qi], fmaf(a1.w, qy[qi], fmaf(a0.w, qx[qi], nrw))); \
            u64 m0 = __ballot(d0 >= hqv);                                               \
            u64 m1 = __ballot(d1 >= hqv);                                               \
            u64 m2 = __ballot(d2 >= hqv);                                               \
            u64 m3 = __ballot(d3 >= hqv);                                               \
            if (m0 | m1 | m2 | m3) {          /* wave-uniform scalar branch */          \
                uint32_t sb = ((qi) * NW + wid) * SEGSZ;                                \
                uint32_t c = scq;                                                       \
                if (d0 >= hqv) { uint32_t s_ = c + mbcnt64(m0);                         \
                                 if (s_ < SEGSZ) mxbuf[sb + s_] = (uint32_t)(base + 0); } \
                c += (uint32_t)__popcll(m0);                                            \
                if (d1 >= hqv) { uint32_t s_ = c + mbcnt64(m1);                         \
                                 if (s_ < SEGSZ) mxbuf[sb + s_] = (uint32_t)(base + 1); } \
                c += (uint32_t)__popcll(m1);                                            \
                if (d2 >= hqv) { uint32_t s_ = c + mbcnt64(m2);                         \
                                 if (s_ < SEGSZ) mxbuf[sb + s_] = (uint32_t)(base + 2); } \
                c += (uint32_t)__popcll(m2);                                            \
                if (d3 >= hqv) { uint32_t s_ = c + mbcnt64(m3);                         \
                                 if (s_ < SEGSZ) mxbuf[sb + s_] = (uint32_t)(base + 3); } \
                c += (uint32_t)__popcll(m3);                                            \
                scq = c;                                                                \
            }                                                                           \
        }
        QPUSH(0, hq0, scq0) QPUSH(1, hq1, scq1) QPUSH(2, hq2, scq2) QPUSH(3, hq3, scq3)
        #undef QPUSH
        site = sn;
    }
    if (lane == 0) {
        scnts[0 * NW + wid] = scq0; scnts[1 * NW + wid] = scq1;
        scnts[2 * NW + wid] = scq2; scnts[3 * NW + wid] = scq3;
    }
    __syncthreads();

    // ---- P4: compact + gather + exact top-16 + loss (wave w -> query w) ----
    if (wid < NQ) {
        int l  = qg * NQ + wid;
        int bl = b * 256 + l;
        if (l == 255) {                    // its top-16 feeds only excluded row 0
            if (lane == 0) partial[bl] = 0.0f;
        } else {
            bool ovf = false;
            uint32_t pref = 0;
            #pragma unroll
            for (int j = 0; j < NW; ++j) {
                uint32_t c = scnts[wid * NW + j];
                ovf = ovf || (c > SEGSZ);
                uint32_t cc = min(c, (uint32_t)SEGSZ);
                if (lane < cc && pref + lane < UCAP)
                    compactb[wid * UCAP + pref + lane] =
                        mxbuf[(wid * NW + j) * SEGSZ + lane];
                pref += cc;
            }
            uint32_t U = pref;
            if (U > UCAP) ovf = true;

            float px1 = pred[(size_t)(bl + 1) * 8 + 0];
            float py1 = pred[(size_t)(bl + 1) * 8 + 1];
            float4 pqv = spool[wid];
            const float* rb = ref + (size_t)b * 3 * HW;

            if (!ovf) {
                // gather candidates (<=4/lane), exact sims, (simkey,pidx)
                uint32_t kh0, kh1, kh2, kh3, kl0, kl1, kl2, kl3;
                #define LOADJ(jj, kh, kl)                                               \
                {                                                                       \
                    uint32_t e = (jj) * 64 + lane;                                      \
                    uint32_t h_ = 0xFFFFFFFFu, l_ = 0xFFFFFFFFu;                        \
                    if (e < U) {                                                        \
                        uint32_t pidx = compactb[wid * UCAP + e];                       \
                        float c0v = rb[pidx], c1v = rb[pidx + HW], c2v = rb[pidx + 2 * HW]; \
                        float rs = exact_rsq(c0v, c1v, c2v);                            \
                        float sx = exact_sim(c0v, c1v, c2v, rs,                         \
                                             pqv.x, pqv.y, pqv.z, pqv.w);               \
                        h_ = fkey(sx); l_ = pidx;                                       \
                    }                                                                   \
                    kh = h_; kl = l_;                                                   \
                }
                LOADJ(0, kh0, kl0) LOADJ(1, kh1, kl1) LOADJ(2, kh2, kl2) LOADJ(3, kh3, kl3)
                #undef LOADJ

                // stage A: smallest H with #{khi <= H} >= 16 (exact; padding
                // 0xFFFFFFFF can't distort since U >= 16 real finite keys)
                uint32_t lo = 0u, hi = 0xFFFFFFFFu;
                #pragma unroll 1
                for (int t = 0; t < 32; ++t) {
                    uint32_t mid = lo + ((hi - lo) >> 1);
                    int c = (int)__popcll(__ballot(kh0 <= mid))
                          + (int)__popcll(__ballot(kh1 <= mid))
                          + (int)__popcll(__ballot(kh2 <= mid))
                          + (int)__popcll(__ballot(kh3 <= mid));
                    if (c >= KK) hi = mid; else lo = mid + 1;
                }
                uint32_t Hh = hi;
                int c1 = (int)__popcll(__ballot(kh0 < Hh))
                       + (int)__popcll(__ballot(kh1 < Hh))
                       + (int)__popcll(__ballot(kh2 < Hh))
                       + (int)__popcll(__ballot(kh3 < Hh));
                u64 e0 = __ballot(kh0 == Hh), e1 = __ballot(kh1 == Hh);
                u64 e2 = __ballot(kh2 == Hh), e3 = __ballot(kh3 == Hh);
                int ec = (int)__popcll(e0) + (int)__popcll(e1)
                       + (int)__popcll(e2) + (int)__popcll(e3);
                int need = KK - c1;                    // 1..16; ec >= need by minimality
                uint32_t Lh = 0xFFFFFFFFu;
                if (ec != need) {
                    // float-tie among sims at the cut (rare): resolve by pidx
                    lo = 0u; hi = 0xFFFFFFFFu;
                    #pragma unroll 1
                    for (int t = 0; t < 32; ++t) {
                        uint32_t mid = lo + ((hi - lo) >> 1);
                        int c = (int)__popcll(e0 & __ballot(kl0 <= mid))
                              + (int)__popcll(e1 & __ballot(kl1 <= mid))
                              + (int)__popcll(e2 & __ballot(kl2 <= mid))
                              + (int)__popcll(e3 & __ballot(kl3 <= mid));
                        if (c >= need) hi = mid; else lo = mid + 1;
                    }
                    Lh = hi;
                }

                // lexicographic min of (ddbits, khi, klo) over the selected 16
                // == argmin over rank-ordered targets, first-min tie-break
                uint32_t bd = 0xFFFFFFFFu, bh = 0xFFFFFFFFu, bo = 0xFFFFFFFFu;
                #define SELJ(kh, kl)                                                    \
                {                                                                       \
                    bool sel = (kh < Hh) || (kh == Hh && kl <= Lh);                     \
                    if (sel) {                                                          \
                        uint32_t idxv = kl;                                             \
                        float tx = (float)(idxv % WW) / 192.0f;                         \
                        float ty = (float)(idxv / WW) / 192.0f;                         \
                        float ddx = __fsub_rn(px1, tx);                                 \
                        float ddy = __fsub_rn(py1, ty);                                 \
                        float dd = __fadd_rn(__fmul_rn(ddx, ddx), __fmul_rn(ddy, ddy)); \
                        uint32_t db = __float_as_uint(dd);   /* dd>=0: monotone */      \
                        bool lt = (db < bd) ||                                          \
                                  (db == bd && (kh < bh || (kh == bh && kl < bo)));     \
                        if (lt) { bd = db; bh = kh; bo = kl; }                          \
                    }                                                                   \
                }
                SELJ(kh0, kl0) SELJ(kh1, kl1) SELJ(kh2, kl2) SELJ(kh3, kl3)
                #undef SELJ
                #pragma unroll
                for (int off = 32; off >= 1; off >>= 1) {
                    uint32_t od = __shfl_xor(bd, off, 64);
                    uint32_t oh = __shfl_xor(bh, off, 64);
                    uint32_t oo = __shfl_xor(bo, off, 64);
                    bool lt = (od < bd) ||
                              (od == bd && (oh < bh || (oh == bh && oo < bo)));
                    if (lt) { bd = od; bh = oh; bo = oo; }
                }
                if (lane == 0) {
                    uint32_t idxv = bo;
                    float tx = (float)(idxv % WW) / 192.0f;
                    float ty = (float)(idxv / WW) / 192.0f;
                    float ex = __fsub_rn(px1, tx);
                    float ey = __fsub_rn(py1, ty);
                    partial[bl] = __fadd_rn(__fmul_rn(ex, ex), __fmul_rn(ey, ey));
                }
            } else {
                // safety net (P ~ 1e-20): exact full rescan for this query
                float dmin = 3.4e38f, btx = 0.0f, bty = 0.0f;
                u64 kept16[KK];
                #pragma unroll
                for (int j = 0; j < KK; ++j) kept16[j] = ~0ull;
                const float4* pg = (const float4*)rb;
                #pragma unroll 1
                for (int st = lane; st < SITES; st += 64) {
                    float4 a0 = pg[st], a1 = pg[st + SITES], a2 = pg[st + 2 * SITES];
                    int base = st * 4;
                    #define FB(comp, ei)                                                \
                    {                                                                   \
                        float rs = exact_rsq(a0.comp, a1.comp, a2.comp);                \
                        float sx = exact_sim(a0.comp, a1.comp, a2.comp, rs,             \
                                             pqv.x, pqv.y, pqv.z, pqv.w);               \
                        u64 key = ((u64)fkey(sx) << 32) | (uint32_t)(base + (ei));      \
                        if (key < kept16[KK - 1]) insert64(kept16, key);                \
                    }
                    FB(x, 0) FB(y, 1) FB(z, 2) FB(w, 3)
                    #undef FB
                }
                #pragma unroll 1
                for (int rnd = 0; rnd < 16; ++rnd) {
                    u64 gm = wave_min_u64(kept16[0]);
                    if (kept16[0] == gm) {        // exactly one lane (unique keys)
                        #pragma unroll
                        for (int j = 0; j < KK - 1; ++j) kept16[j] = kept16[j + 1];
                        kept16[KK - 1] = ~0ull;
                    }
                    LOSS_STEP(gm)
                }
                if (lane == 0) {
                    float ex = __fsub_rn(px1, btx);
                    float ey = __fsub_rn(py1, bty);
                    partial[bl] = __fadd_rn(__fmul_rn(ex, ex), __fmul_rn(ey, ey));
                }
            }
        }
    }
}

// ---------- reduce 2048 partials -> mean ----------
__global__ __launch_bounds__(256) void reduce_kernel(const float* __restrict__ partial,
                                                     float* __restrict__ out) {
    __shared__ double sred[256];
    double a = 0.0;
    #pragma unroll
    for (int i = 0; i < 8; ++i) a += (double)partial[i * 256 + threadIdx.x];
    sred[threadIdx.x] = a;
    __syncthreads();
    for (int s = 128; s > 0; s >>= 1) {
        if (threadIdx.x < s) sred[threadIdx.x] += sred[threadIdx.x + s];
        __syncthreads();
    }
    if (threadIdx.x == 0) out[0] = (float)(sred[0] / 2040.0);
}

// ---------- launch ----------
extern "C" void kernel_launch(void* const* d_in, const int* in_sizes, int n_in,
                              void* d_out, int out_size, void* d_ws, size_t ws_size,
                              hipStream_t stream) {
    const float* pred = (const float*)d_in[0];   // (8,256,8) f32
    const float* ref  = (const float*)d_in[1];   // (8,3,192,192) f32
    float* out = (float*)d_out;

    float* partial = (float*)d_ws;               // 2048 floats, fully overwritten

    fused_kernel <<<512, 1024, 0, stream>>>(pred, ref, partial);
    reduce_kernel<<<  1,  256, 0, stream>>>(partial, out);
}